// Round 1
// baseline (838.538 us; speedup 1.0000x reference)
//
#include <hip/hip_runtime.h>
#include <math.h>

#define NN 10000       // nodes per graph
#define NE 160000      // edges per graph
#define DD 512         // feature dim

// ---------------------------------------------------------------------------
// init: zero edge counts, cursors, mean accumulators
__global__ void k_init(int* cnt, int* cursor, float* u) {
    int i = blockIdx.x * blockDim.x + threadIdx.x;
    if (i < 2 * NN) { cnt[i] = 0; cursor[i] = 0; }
    if (i < 2 * DD) u[i] = 0.f;
}

// count in-degree (real edges only; self-loop handled as +1 later)
__global__ void k_count(const int* e1, const int* e2, int* cnt) {
    int i = blockIdx.x * blockDim.x + threadIdx.x;
    if (i < NE) {
        atomicAdd(&cnt[e1[NE + i]], 1);
    } else if (i < 2 * NE) {
        int e = i - NE;
        atomicAdd(&cnt[NN + e2[NE + e]], 1);
    }
}

__global__ void k_dinv(const int* cnt, float* dinv) {
    int i = blockIdx.x * blockDim.x + threadIdx.x;
    if (i < 2 * NN) dinv[i] = rsqrtf((float)(cnt[i] + 1));
}

// exclusive scan of per-node edge counts -> CSR offsets. One block per graph.
__global__ void k_scan(const int* cnt, int* offs) {
    int g = blockIdx.x;
    const int* c = cnt + g * NN;
    int* o = offs + g * (NN + 1);
    __shared__ int sums[1024];
    int t = threadIdx.x;                  // 1024 threads
    const int PER = 10;                   // 1024*10 >= NN
    int base = t * PER;
    int vals[PER];
    int local = 0;
    #pragma unroll
    for (int j = 0; j < PER; ++j) {
        int idx = base + j;
        int v = (idx < NN) ? c[idx] : 0;
        vals[j] = v; local += v;
    }
    sums[t] = local;
    __syncthreads();
    for (int off = 1; off < 1024; off <<= 1) {
        int v = (t >= off) ? sums[t - off] : 0;
        __syncthreads();
        sums[t] += v;
        __syncthreads();
    }
    int prefix = (t > 0) ? sums[t - 1] : 0;   // exclusive
    #pragma unroll
    for (int j = 0; j < PER; ++j) {
        int idx = base + j;
        if (idx < NN) { o[idx] = prefix; prefix += vals[j]; }
    }
    if (t == 1023) o[NN] = sums[1023];
}

// scatter edges into CSR buckets (adj holds SRC node per incoming edge of dst)
__global__ void k_fill(const int* e1, const int* e2, const int* offs,
                       int* cursor, int* adj) {
    int i = blockIdx.x * blockDim.x + threadIdx.x;
    if (i >= 2 * NE) return;
    int g = (i < NE) ? 0 : 1;
    int e = i - g * NE;
    const int* ei = g ? e2 : e1;
    int s = ei[e];
    int d = ei[NE + e];
    int pos = atomicAdd(&cursor[g * NN + d], 1);
    adj[g * NE + offs[g * (NN + 1) + d] + pos] = s;
}

// ---------------------------------------------------------------------------
// fp32 GEMM: C[M x 512] = A[M x 512] * W[512 x 512]
// A rows < NN come from A0, rows >= NN from A1 (lets us batch both graphs).
// 64x64 tile, 256 threads, 4x4 per thread, LDS pad 68 floats (16B aligned rows).
__global__ __launch_bounds__(256) void k_gemm(const float* __restrict__ A0,
                                              const float* __restrict__ A1,
                                              const float* __restrict__ W,
                                              float* __restrict__ C, int M) {
    __shared__ float As[16][68];
    __shared__ float Bs[16][68];
    int tid = threadIdx.x;
    int tx = tid & 15, ty = tid >> 4;
    int row0 = blockIdx.x * 64, col0 = blockIdx.y * 64;

    float acc[4][4] = {};
    for (int k0 = 0; k0 < DD; k0 += 16) {
        // A tile: thread loads 4 consecutive k of one row, stores transposed
        {
            int r = tid >> 2;
            int kk4 = (tid & 3) * 4;
            int grow = row0 + r;
            float4 av = make_float4(0.f, 0.f, 0.f, 0.f);
            if (grow < M) {
                const float* Arow = (grow < NN) ? (A0 + (size_t)grow * DD)
                                                : (A1 + (size_t)(grow - NN) * DD);
                av = *reinterpret_cast<const float4*>(Arow + k0 + kk4);
            }
            As[kk4 + 0][r] = av.x;
            As[kk4 + 1][r] = av.y;
            As[kk4 + 2][r] = av.z;
            As[kk4 + 3][r] = av.w;
        }
        // B tile: thread loads 4 consecutive cols of one k-row
        {
            int kk = tid >> 4;
            int c4 = (tid & 15) * 4;
            float4 bv = *reinterpret_cast<const float4*>(W + (size_t)(k0 + kk) * DD + col0 + c4);
            Bs[kk][c4 + 0] = bv.x;
            Bs[kk][c4 + 1] = bv.y;
            Bs[kk][c4 + 2] = bv.z;
            Bs[kk][c4 + 3] = bv.w;
        }
        __syncthreads();
        #pragma unroll
        for (int kk = 0; kk < 16; ++kk) {
            float4 a4 = *reinterpret_cast<const float4*>(&As[kk][ty * 4]);
            float4 b4 = *reinterpret_cast<const float4*>(&Bs[kk][tx * 4]);
            float a[4] = {a4.x, a4.y, a4.z, a4.w};
            float b[4] = {b4.x, b4.y, b4.z, b4.w};
            #pragma unroll
            for (int i = 0; i < 4; ++i)
                #pragma unroll
                for (int j = 0; j < 4; ++j)
                    acc[i][j] = fmaf(a[i], b[j], acc[i][j]);
        }
        __syncthreads();
    }
    #pragma unroll
    for (int i = 0; i < 4; ++i) {
        int r = row0 + ty * 4 + i;
        if (r < M) {
            float4 o = make_float4(acc[i][0], acc[i][1], acc[i][2], acc[i][3]);
            *reinterpret_cast<float4*>(C + (size_t)r * DD + col0 + tx * 4) = o;
        }
    }
}

// ---------------------------------------------------------------------------
// aggregation: out[v] = maybe_relu( dinv[v] * (sum_{s->v} h[s]*dinv[s] + h[v]*dinv[v]) + b )
// one block (256 thr) per node; thread owns 2 columns (float2).
template <bool RELU>
__global__ __launch_bounds__(256) void k_agg(const float* __restrict__ h,
                                             const int* __restrict__ adj,
                                             const int* __restrict__ offs,
                                             const float* __restrict__ dinv,
                                             const float* __restrict__ bias,
                                             float* __restrict__ out) {
    int v = blockIdx.x;                  // 0 .. 2*NN-1
    int g = (v < NN) ? 0 : 1;
    int vl = v - g * NN;
    int c = threadIdx.x * 2;
    const int* o = offs + g * (NN + 1);
    int beg = o[vl], end = o[vl + 1];
    const int* a = adj + g * NE;
    float dv = dinv[v];

    float2 hv = *reinterpret_cast<const float2*>(h + (size_t)v * DD + c);
    float accx = hv.x * dv, accy = hv.y * dv;   // self-loop term
    for (int e = beg; e < end; ++e) {
        int s = a[e] + g * NN;
        float ds = dinv[s];
        float2 hs = *reinterpret_cast<const float2*>(h + (size_t)s * DD + c);
        accx = fmaf(hs.x, ds, accx);
        accy = fmaf(hs.y, ds, accy);
    }
    float2 bb = *reinterpret_cast<const float2*>(bias + c);
    float ox = fmaf(accx, dv, bb.x);
    float oy = fmaf(accy, dv, bb.y);
    if (RELU) { ox = fmaxf(ox, 0.f); oy = fmaxf(oy, 0.f); }
    *reinterpret_cast<float2*>(out + (size_t)v * DD + c) = make_float2(ox, oy);
}

// partial column sums for the per-graph mean
__global__ void k_meanpart(const float* __restrict__ h, float* __restrict__ u) {
    int g = blockIdx.y;
    int chunk = blockIdx.x;              // 0..31
    const int rows_per = (NN + 31) / 32; // 313
    int r0 = chunk * rows_per;
    int r1 = min(r0 + rows_per, NN);
    int c = threadIdx.x * 2;
    float accx = 0.f, accy = 0.f;
    for (int r = r0; r < r1; ++r) {
        float2 hv = *reinterpret_cast<const float2*>(h + (size_t)(g * NN + r) * DD + c);
        accx += hv.x; accy += hv.y;
    }
    atomicAdd(&u[g * DD + c], accx);
    atomicAdd(&u[g * DD + c + 1], accy);
}

// comparison head: z = [u1,u2]/NN ; h = relu(z@Wf1 + bf1) ; out = sigmoid(h@Wf2 + bf2)
__global__ void k_head(const float* __restrict__ u,
                       const float* __restrict__ Wf1, const float* __restrict__ bf1,
                       const float* __restrict__ Wf2, const float* __restrict__ bf2,
                       float* __restrict__ outp) {
    __shared__ float z[2 * DD];
    __shared__ float red[DD];
    int t = threadIdx.x;                 // 512
    const float inv = 1.0f / (float)NN;
    z[t] = u[t] * inv;
    z[t + DD] = u[t + DD] * inv;
    __syncthreads();
    float acc = bf1[t];
    for (int k = 0; k < 2 * DD; ++k)
        acc = fmaf(z[k], Wf1[(size_t)k * DD + t], acc);
    acc = fmaxf(acc, 0.f);
    red[t] = acc * Wf2[t];
    __syncthreads();
    for (int s = DD / 2; s > 0; s >>= 1) {
        if (t < s) red[t] += red[t + s];
        __syncthreads();
    }
    if (t == 0) outp[0] = 1.f / (1.f + expf(-(red[0] + bf2[0])));
}

// ---------------------------------------------------------------------------
extern "C" void kernel_launch(void* const* d_in, const int* in_sizes, int n_in,
                              void* d_out, int out_size, void* d_ws, size_t ws_size,
                              hipStream_t stream) {
    const float* x1  = (const float*)d_in[0];
    const float* x2  = (const float*)d_in[1];
    const int*   e1  = (const int*)d_in[2];
    const int*   e2  = (const int*)d_in[3];
    const float* W1  = (const float*)d_in[4];
    const float* W2  = (const float*)d_in[5];
    const float* W3  = (const float*)d_in[6];
    const float* b1  = (const float*)d_in[7];
    const float* b2  = (const float*)d_in[8];
    const float* b3  = (const float*)d_in[9];
    const float* Wf1 = (const float*)d_in[10];
    const float* bf1 = (const float*)d_in[11];
    const float* Wf2 = (const float*)d_in[12];
    const float* bf2 = (const float*)d_in[13];
    float* outp = (float*)d_out;

    // workspace carve-up
    char* w = (char*)d_ws;
    float* hbuf0 = (float*)w;  w += (size_t)2 * NN * DD * 4;   // 40.96 MB
    float* hbuf1 = (float*)w;  w += (size_t)2 * NN * DD * 4;   // 40.96 MB
    int*   cnt    = (int*)w;   w += 2 * NN * 4;
    int*   cursor = (int*)w;   w += 2 * NN * 4;
    int*   offs   = (int*)w;   w += 2 * (NN + 1) * 4 + 8;      // pad to 16B
    int*   adj    = (int*)w;   w += 2 * NE * 4;
    float* dinv   = (float*)w; w += 2 * NN * 4;
    float* u      = (float*)w; w += 2 * DD * 4;

    const int M = 2 * NN;

    // graph preprocessing
    k_init<<<(2 * NN + 255) / 256, 256, 0, stream>>>(cnt, cursor, u);
    k_count<<<(2 * NE + 255) / 256, 256, 0, stream>>>(e1, e2, cnt);
    k_dinv<<<(2 * NN + 255) / 256, 256, 0, stream>>>(cnt, dinv);
    k_scan<<<2, 1024, 0, stream>>>(cnt, offs);
    k_fill<<<(2 * NE + 255) / 256, 256, 0, stream>>>(e1, e2, offs, cursor, adj);

    dim3 ggrid((M + 63) / 64, DD / 64);

    // layer 1
    k_gemm<<<ggrid, 256, 0, stream>>>(x1, x2, W1, hbuf0, M);
    k_agg<true><<<M, 256, 0, stream>>>(hbuf0, adj, offs, dinv, b1, hbuf1);
    // layer 2
    k_gemm<<<ggrid, 256, 0, stream>>>(hbuf1, hbuf1 + (size_t)NN * DD, W2, hbuf0, M);
    k_agg<true><<<M, 256, 0, stream>>>(hbuf0, adj, offs, dinv, b2, hbuf1);
    // layer 3
    k_gemm<<<ggrid, 256, 0, stream>>>(hbuf1, hbuf1 + (size_t)NN * DD, W3, hbuf0, M);
    k_agg<false><<<M, 256, 0, stream>>>(hbuf0, adj, offs, dinv, b3, hbuf1);

    // mean + head
    k_meanpart<<<dim3(32, 2), 256, 0, stream>>>(hbuf1, u);
    k_head<<<1, DD, 0, stream>>>(u, Wf1, bf1, Wf2, bf2, outp);
}

// Round 2
// 404.364 us; speedup vs baseline: 2.0737x; 2.0737x over previous
//
#include <hip/hip_runtime.h>
#include <math.h>

#define NN 10000       // nodes per graph
#define NE 160000      // edges per graph
#define DD 512         // feature dim
#define MPAD 20096     // 157 * 128 rows (padded batched M)

typedef __attribute__((ext_vector_type(8))) short bf16x8;
typedef __attribute__((ext_vector_type(4))) float f32x4;
typedef __attribute__((ext_vector_type(8))) unsigned short u16x8;

__device__ __forceinline__ unsigned short f2bf(float f) {
    unsigned u = __float_as_uint(f);
    u += 0x7FFFu + ((u >> 16) & 1u);          // round-to-nearest-even
    return (unsigned short)(u >> 16);
}
__device__ __forceinline__ float bf2f(unsigned short h) {
    return __uint_as_float(((unsigned)h) << 16);
}

// async global->LDS, 16B per lane; LDS dest is wave-uniform base + lane*16
#define GLOAD16(g, l) __builtin_amdgcn_global_load_lds( \
    (const __attribute__((address_space(1))) void*)(unsigned long long)(const void*)(g), \
    (__attribute__((address_space(3))) void*)(unsigned)(unsigned long long)(void*)(l), \
    16, 0, 0)

// ---------------------------------------------------------------------------
// init: zero edge counts, cursors, mean accumulators, head accumulator
__global__ void k_init(int* cnt, int* cursor, float* u, float* hacc) {
    int i = blockIdx.x * blockDim.x + threadIdx.x;
    if (i < 2 * NN) { cnt[i] = 0; cursor[i] = 0; }
    if (i < 2 * DD) u[i] = 0.f;
    if (i < DD) hacc[i] = 0.f;
}

// count in-degree (real edges only; self-loop handled as +1 later)
__global__ void k_count(const int* e1, const int* e2, int* cnt) {
    int i = blockIdx.x * blockDim.x + threadIdx.x;
    if (i < NE) {
        atomicAdd(&cnt[e1[NE + i]], 1);
    } else if (i < 2 * NE) {
        int e = i - NE;
        atomicAdd(&cnt[NN + e2[NE + e]], 1);
    }
}

__global__ void k_dinv(const int* cnt, float* dinv) {
    int i = blockIdx.x * blockDim.x + threadIdx.x;
    if (i < 2 * NN) dinv[i] = rsqrtf((float)(cnt[i] + 1));
}

// exclusive scan of per-node edge counts -> CSR offsets. One block per graph.
__global__ void k_scan(const int* cnt, int* offs) {
    int g = blockIdx.x;
    const int* c = cnt + g * NN;
    int* o = offs + g * (NN + 1);
    __shared__ int sums[1024];
    int t = threadIdx.x;                  // 1024 threads
    const int PER = 10;                   // 1024*10 >= NN
    int base = t * PER;
    int vals[PER];
    int local = 0;
    #pragma unroll
    for (int j = 0; j < PER; ++j) {
        int idx = base + j;
        int v = (idx < NN) ? c[idx] : 0;
        vals[j] = v; local += v;
    }
    sums[t] = local;
    __syncthreads();
    for (int off = 1; off < 1024; off <<= 1) {
        int v = (t >= off) ? sums[t - off] : 0;
        __syncthreads();
        sums[t] += v;
        __syncthreads();
    }
    int prefix = (t > 0) ? sums[t - 1] : 0;   // exclusive
    #pragma unroll
    for (int j = 0; j < PER; ++j) {
        int idx = base + j;
        if (idx < NN) { o[idx] = prefix; prefix += vals[j]; }
    }
    if (t == 1023) o[NN] = sums[1023];
}

// scatter edges into CSR buckets (adj holds SRC node per incoming edge of dst)
__global__ void k_fill(const int* e1, const int* e2, const int* offs,
                       int* cursor, int* adj) {
    int i = blockIdx.x * blockDim.x + threadIdx.x;
    if (i >= 2 * NE) return;
    int g = (i < NE) ? 0 : 1;
    int e = i - g * NE;
    const int* ei = g ? e2 : e1;
    int s = ei[e];
    int d = ei[NE + e];
    int pos = atomicAdd(&cursor[g * NN + d], 1);
    adj[g * NE + offs[g * (NN + 1) + d] + pos] = s;
}

// ---------------------------------------------------------------------------
// fp32 -> bf16 convert of node features, both graphs batched, tail rows zeroed
__global__ void k_cvt_x(const float* __restrict__ x1, const float* __restrict__ x2,
                        unsigned short* __restrict__ xb) {
    long long gid = (long long)blockIdx.x * 256 + threadIdx.x;
    long long i8 = gid * 8;
    if (i8 >= (long long)MPAD * DD) return;
    int row = (int)(i8 >> 9);
    int col = (int)(i8 & 511);
    u16x8 ov;
    if (row < 2 * NN) {
        const float* src = (row < NN) ? (x1 + (size_t)row * DD + col)
                                      : (x2 + (size_t)(row - NN) * DD + col);
        float4 f0 = ((const float4*)src)[0];
        float4 f1 = ((const float4*)src)[1];
        ov[0] = f2bf(f0.x); ov[1] = f2bf(f0.y); ov[2] = f2bf(f0.z); ov[3] = f2bf(f0.w);
        ov[4] = f2bf(f1.x); ov[5] = f2bf(f1.y); ov[6] = f2bf(f1.z); ov[7] = f2bf(f1.w);
    } else {
        #pragma unroll
        for (int j = 0; j < 8; ++j) ov[j] = 0;
    }
    *(u16x8*)(xb + i8) = ov;
}

// W[k][n] fp32 -> Wt[n][k] bf16 (transpose so B-fragments load like A-fragments)
__global__ void k_cvt_w(const float* __restrict__ W1, const float* __restrict__ W2,
                        const float* __restrict__ W3, unsigned short* __restrict__ Wt) {
    __shared__ float t[32][33];
    const float* W = (blockIdx.z == 0) ? W1 : (blockIdx.z == 1) ? W2 : W3;
    unsigned short* o = Wt + (size_t)blockIdx.z * DD * DD;
    int n0 = blockIdx.x * 32, k0 = blockIdx.y * 32;
    int tx = threadIdx.x, ty = threadIdx.y;
    t[ty][tx] = W[(size_t)(k0 + ty) * DD + n0 + tx];
    __syncthreads();
    o[(size_t)(n0 + ty) * DD + k0 + tx] = f2bf(t[tx][ty]);
}

// ---------------------------------------------------------------------------
// bf16 MFMA GEMM: C[M x 512] = A[M x 512] * W[512 x 512], W given transposed.
// 128x128 tile, 4 waves (2x2), BK=32, 16x16x32 MFMA, global_load_lds width-16.
// LDS layout: 16B chunks at (kb*128 + row)*16 -> conflict-free ds_read_b128
// and linear lane->LDS mapping for global_load_lds (G21).
__global__ __launch_bounds__(256) void k_gemm(const unsigned short* __restrict__ A,
                                              const unsigned short* __restrict__ Bt,
                                              unsigned short* __restrict__ C, int M) {
    __shared__ bf16x8 As[512];   // 8 KB
    __shared__ bf16x8 Bs[512];   // 8 KB
    int tid = threadIdx.x;
    int lane = tid & 63;
    int wid = tid >> 6;
    int wr = wid >> 1, wc = wid & 1;
    int row0 = blockIdx.x * 128;
    int col0 = blockIdx.y * 128;

    // staging chunks: instr s in {0,1}: chunk = (s*4 + wid)*64 + lane
    int ch0 = wid * 64 + lane;
    int ch1 = 256 + wid * 64 + lane;
    const unsigned short* gA0 = A + (size_t)(row0 + (ch0 & 127)) * DD + (ch0 >> 7) * 8;
    const unsigned short* gA1 = A + (size_t)(row0 + (ch1 & 127)) * DD + (ch1 >> 7) * 8;
    const unsigned short* gB0 = Bt + (size_t)(col0 + (ch0 & 127)) * DD + (ch0 >> 7) * 8;
    const unsigned short* gB1 = Bt + (size_t)(col0 + (ch1 & 127)) * DD + (ch1 >> 7) * 8;

    // fragment LDS indices (fixed across K-loop)
    int iA[4], iB[4];
    #pragma unroll
    for (int m = 0; m < 4; ++m) {
        iA[m] = (lane >> 4) * 128 + wr * 64 + m * 16 + (lane & 15);
        iB[m] = (lane >> 4) * 128 + wc * 64 + m * 16 + (lane & 15);
    }

    f32x4 acc[4][4];
    #pragma unroll
    for (int m = 0; m < 4; ++m)
        #pragma unroll
        for (int n = 0; n < 4; ++n)
            acc[m][n] = (f32x4){0.f, 0.f, 0.f, 0.f};

    for (int k0 = 0; k0 < DD; k0 += 32) {
        GLOAD16(gA0, &As[wid * 64]);
        GLOAD16(gA1, &As[256 + wid * 64]);
        GLOAD16(gB0, &Bs[wid * 64]);
        GLOAD16(gB1, &Bs[256 + wid * 64]);
        gA0 += 32; gA1 += 32; gB0 += 32; gB1 += 32;
        __syncthreads();                       // drain vmcnt + barrier
        bf16x8 af[4], bfr[4];
        #pragma unroll
        for (int m = 0; m < 4; ++m) { af[m] = As[iA[m]]; bfr[m] = Bs[iB[m]]; }
        #pragma unroll
        for (int m = 0; m < 4; ++m)
            #pragma unroll
            for (int n = 0; n < 4; ++n)
                acc[m][n] = __builtin_amdgcn_mfma_f32_16x16x32_bf16(af[m], bfr[n], acc[m][n], 0, 0, 0);
        __syncthreads();                       // protect LDS before next stage
    }

    // epilogue: C/D layout col = lane&15, row = (lane>>4)*4 + i  [m89]
    #pragma unroll
    for (int m = 0; m < 4; ++m) {
        int rbase = row0 + wr * 64 + m * 16 + (lane >> 4) * 4;
        #pragma unroll
        for (int n = 0; n < 4; ++n) {
            int col = col0 + wc * 64 + n * 16 + (lane & 15);
            f32x4 v = acc[m][n];
            #pragma unroll
            for (int i = 0; i < 4; ++i) {
                int r = rbase + i;
                if (r < M) C[(size_t)r * DD + col] = f2bf(v[i]);
            }
        }
    }
}

// ---------------------------------------------------------------------------
// aggregation: out[v] = maybe_relu( dv*(sum_{s->v} h[s]*ds + h[v]*dv) + b )
// one wave per node, lane owns 8 cols (16B ushort8 loads), fp32 accumulate
template <bool RELU>
__global__ __launch_bounds__(256) void k_agg(const unsigned short* __restrict__ h,
                                             const int* __restrict__ adj,
                                             const int* __restrict__ offs,
                                             const float* __restrict__ dinv,
                                             const float* __restrict__ bias,
                                             unsigned short* __restrict__ out) {
    int wid = threadIdx.x >> 6;
    int lane = threadIdx.x & 63;
    int v = blockIdx.x * 4 + wid;       // 0 .. 2*NN-1 (grid exact)
    int g = (v < NN) ? 0 : 1;
    int vl = v - g * NN;
    const int* o = offs + g * (NN + 1);
    int beg = o[vl], end = o[vl + 1];
    const int* a = adj + g * NE;
    float dv = dinv[v];
    int c = lane * 8;

    u16x8 hv = *(const u16x8*)(h + (size_t)v * DD + c);
    float acc[8];
    #pragma unroll
    for (int j = 0; j < 8; ++j) acc[j] = bf2f(hv[j]) * dv;   // self-loop term

    for (int e = beg; e < end; ++e) {
        int s = a[e] + g * NN;
        float ds = dinv[s];
        u16x8 hs = *(const u16x8*)(h + (size_t)s * DD + c);
        #pragma unroll
        for (int j = 0; j < 8; ++j) acc[j] = fmaf(bf2f(hs[j]), ds, acc[j]);
    }

    float4 b0 = ((const float4*)(bias + c))[0];
    float4 b1 = ((const float4*)(bias + c))[1];
    float bb[8] = {b0.x, b0.y, b0.z, b0.w, b1.x, b1.y, b1.z, b1.w};
    u16x8 ov;
    #pragma unroll
    for (int j = 0; j < 8; ++j) {
        float x = fmaf(acc[j], dv, bb[j]);
        if (RELU) x = fmaxf(x, 0.f);
        ov[j] = f2bf(x);
    }
    *(u16x8*)(out + (size_t)v * DD + c) = ov;
}

// partial column sums for the per-graph mean (bf16 input)
__global__ void k_meanpart(const unsigned short* __restrict__ h, float* __restrict__ u) {
    int g = blockIdx.y;
    int chunk = blockIdx.x;              // 0..31
    const int rows_per = (NN + 31) / 32; // 313
    int r0 = chunk * rows_per;
    int r1 = min(r0 + rows_per, NN);
    int c = threadIdx.x * 2;
    float ax = 0.f, ay = 0.f;
    for (int r = r0; r < r1; ++r) {
        const unsigned short* p = h + (size_t)(g * NN + r) * DD + c;
        ax += bf2f(p[0]); ay += bf2f(p[1]);
    }
    atomicAdd(&u[g * DD + c], ax);
    atomicAdd(&u[g * DD + c + 1], ay);
}

// head part 1: hacc[t] += sum_k z[k] * Wf1[k][t], k split over 8 blocks
__global__ void k_head1(const float* __restrict__ u, const float* __restrict__ Wf1,
                        float* __restrict__ hacc) {
    int t = threadIdx.x;                 // 512
    int kb = blockIdx.x;                 // 8 blocks x 128 k
    const float inv = 1.0f / (float)NN;
    float acc = 0.f;
    for (int k = kb * 128; k < kb * 128 + 128; ++k) {
        float z = u[k] * inv;
        acc = fmaf(z, Wf1[(size_t)k * DD + t], acc);
    }
    atomicAdd(&hacc[t], acc);
}

// head part 2: relu + dot + sigmoid
__global__ void k_head2(const float* __restrict__ hacc, const float* __restrict__ bf1,
                        const float* __restrict__ Wf2, const float* __restrict__ bf2,
                        float* __restrict__ outp) {
    __shared__ float red[DD];
    int t = threadIdx.x;                 // 512
    float hv = fmaxf(hacc[t] + bf1[t], 0.f);
    red[t] = hv * Wf2[t];
    __syncthreads();
    for (int s = DD / 2; s > 0; s >>= 1) {
        if (t < s) red[t] += red[t + s];
        __syncthreads();
    }
    if (t == 0) outp[0] = 1.f / (1.f + expf(-(red[0] + bf2[0])));
}

// ---------------------------------------------------------------------------
extern "C" void kernel_launch(void* const* d_in, const int* in_sizes, int n_in,
                              void* d_out, int out_size, void* d_ws, size_t ws_size,
                              hipStream_t stream) {
    const float* x1  = (const float*)d_in[0];
    const float* x2  = (const float*)d_in[1];
    const int*   e1  = (const int*)d_in[2];
    const int*   e2  = (const int*)d_in[3];
    const float* W1  = (const float*)d_in[4];
    const float* W2  = (const float*)d_in[5];
    const float* W3  = (const float*)d_in[6];
    const float* b1  = (const float*)d_in[7];
    const float* b2  = (const float*)d_in[8];
    const float* b3  = (const float*)d_in[9];
    const float* Wf1 = (const float*)d_in[10];
    const float* bf1 = (const float*)d_in[11];
    const float* Wf2 = (const float*)d_in[12];
    const float* bf2 = (const float*)d_in[13];
    float* outp = (float*)d_out;

    // workspace carve-up (16B-aligned chunks)
    char* w = (char*)d_ws;
    unsigned short* xb = (unsigned short*)w; w += (size_t)MPAD * DD * 2;   // 20.6 MB
    unsigned short* hG = (unsigned short*)w; w += (size_t)MPAD * DD * 2;   // 20.6 MB
    unsigned short* hA = (unsigned short*)w; w += (size_t)MPAD * DD * 2;   // 20.6 MB
    unsigned short* Wt = (unsigned short*)w; w += (size_t)3 * DD * DD * 2; // 1.5 MB
    int*   cnt    = (int*)w;   w += 2 * NN * 4;
    int*   cursor = (int*)w;   w += 2 * NN * 4;
    int*   offs   = (int*)w;   w += 2 * (NN + 1) * 4 + 8;
    int*   adj    = (int*)w;   w += 2 * NE * 4;
    float* dinv   = (float*)w; w += 2 * NN * 4;
    float* u      = (float*)w; w += 2 * DD * 4;
    float* hacc   = (float*)w; w += DD * 4;

    const int M = 2 * NN;

    // graph preprocessing + conversions
    k_init<<<(2 * NN + 255) / 256, 256, 0, stream>>>(cnt, cursor, u, hacc);
    k_count<<<(2 * NE + 255) / 256, 256, 0, stream>>>(e1, e2, cnt);
    k_dinv<<<(2 * NN + 255) / 256, 256, 0, stream>>>(cnt, dinv);
    k_scan<<<2, 1024, 0, stream>>>(cnt, offs);
    k_fill<<<(2 * NE + 255) / 256, 256, 0, stream>>>(e1, e2, offs, cursor, adj);
    k_cvt_x<<<(MPAD * DD / 8 + 255) / 256, 256, 0, stream>>>(x1, x2, xb);
    k_cvt_w<<<dim3(16, 16, 3), dim3(32, 32), 0, stream>>>(W1, W2, W3, Wt);

    dim3 ggrid(MPAD / 128, DD / 128);   // 157 x 4

    // layer 1
    k_gemm<<<ggrid, 256, 0, stream>>>(xb, Wt, hG, M);
    k_agg<true><<<M / 4, 256, 0, stream>>>(hG, adj, offs, dinv, b1, hA);
    // layer 2
    k_gemm<<<ggrid, 256, 0, stream>>>(hA, Wt + (size_t)DD * DD, hG, M);
    k_agg<true><<<M / 4, 256, 0, stream>>>(hG, adj, offs, dinv, b2, hA);
    // layer 3
    k_gemm<<<ggrid, 256, 0, stream>>>(hA, Wt + (size_t)2 * DD * DD, hG, M);
    k_agg<false><<<M / 4, 256, 0, stream>>>(hG, adj, offs, dinv, b3, hA);

    // mean + head
    k_meanpart<<<dim3(32, 2), 256, 0, stream>>>(hA, u);
    k_head1<<<8, DD, 0, stream>>>(u, Wf1, hacc);
    k_head2<<<1, DD, 0, stream>>>(hacc, bf1, Wf2, bf2, outp);
}

// Round 3
// 330.084 us; speedup vs baseline: 2.5404x; 1.2250x over previous
//
#include <hip/hip_runtime.h>
#include <math.h>

#define NN 10000       // nodes per graph
#define NE 160000      // edges per graph
#define DD 512         // feature dim
#define MPAD 20096     // 157 * 128 rows (padded batched M)

typedef __attribute__((ext_vector_type(8))) short bf16x8;
typedef __attribute__((ext_vector_type(4))) float f32x4;
typedef __attribute__((ext_vector_type(8))) unsigned short u16x8;

__device__ __forceinline__ unsigned short f2bf(float f) {
    unsigned u = __float_as_uint(f);
    u += 0x7FFFu + ((u >> 16) & 1u);          // round-to-nearest-even
    return (unsigned short)(u >> 16);
}
__device__ __forceinline__ float bf2f(unsigned short h) {
    return __uint_as_float(((unsigned)h) << 16);
}

// async global->LDS, 16B per lane; LDS dest is wave-uniform base + lane*16
#define GLOAD16(g, l) __builtin_amdgcn_global_load_lds( \
    (const __attribute__((address_space(1))) void*)(unsigned long long)(const void*)(g), \
    (__attribute__((address_space(3))) void*)(unsigned)(unsigned long long)(void*)(l), \
    16, 0, 0)

// ---------------------------------------------------------------------------
// init: zero edge counts, cursors, mean accumulators, head accumulator
__global__ void k_init(int* cnt, int* cursor, float* u, float* hacc) {
    int i = blockIdx.x * blockDim.x + threadIdx.x;
    if (i < 2 * NN) { cnt[i] = 0; cursor[i] = 0; }
    if (i < 2 * DD) u[i] = 0.f;
    if (i < DD) hacc[i] = 0.f;
}

// count in-degree (real edges only; self-loop handled as +1 later)
__global__ void k_count(const int* e1, const int* e2, int* cnt) {
    int i = blockIdx.x * blockDim.x + threadIdx.x;
    if (i < NE) {
        atomicAdd(&cnt[e1[NE + i]], 1);
    } else if (i < 2 * NE) {
        int e = i - NE;
        atomicAdd(&cnt[NN + e2[NE + e]], 1);
    }
}

__global__ void k_dinv(const int* cnt, float* dinv) {
    int i = blockIdx.x * blockDim.x + threadIdx.x;
    if (i < 2 * NN) dinv[i] = rsqrtf((float)(cnt[i] + 1));
}

// exclusive scan of per-node edge counts -> CSR offsets. One block per graph.
__global__ void k_scan(const int* cnt, int* offs) {
    int g = blockIdx.x;
    const int* c = cnt + g * NN;
    int* o = offs + g * (NN + 1);
    __shared__ int sums[1024];
    int t = threadIdx.x;                  // 1024 threads
    const int PER = 10;                   // 1024*10 >= NN
    int base = t * PER;
    int vals[PER];
    int local = 0;
    #pragma unroll
    for (int j = 0; j < PER; ++j) {
        int idx = base + j;
        int v = (idx < NN) ? c[idx] : 0;
        vals[j] = v; local += v;
    }
    sums[t] = local;
    __syncthreads();
    for (int off = 1; off < 1024; off <<= 1) {
        int v = (t >= off) ? sums[t - off] : 0;
        __syncthreads();
        sums[t] += v;
        __syncthreads();
    }
    int prefix = (t > 0) ? sums[t - 1] : 0;   // exclusive
    #pragma unroll
    for (int j = 0; j < PER; ++j) {
        int idx = base + j;
        if (idx < NN) { o[idx] = prefix; prefix += vals[j]; }
    }
    if (t == 1023) o[NN] = sums[1023];
}

// scatter edges into CSR buckets (adj holds SRC node per incoming edge of dst)
__global__ void k_fill(const int* e1, const int* e2, const int* offs,
                       int* cursor, int* adj) {
    int i = blockIdx.x * blockDim.x + threadIdx.x;
    if (i >= 2 * NE) return;
    int g = (i < NE) ? 0 : 1;
    int e = i - g * NE;
    const int* ei = g ? e2 : e1;
    int s = ei[e];
    int d = ei[NE + e];
    int pos = atomicAdd(&cursor[g * NN + d], 1);
    adj[g * NE + offs[g * (NN + 1) + d] + pos] = s;
}

// ---------------------------------------------------------------------------
// fp32 -> bf16 convert of node features, both graphs batched, tail rows zeroed
__global__ void k_cvt_x(const float* __restrict__ x1, const float* __restrict__ x2,
                        unsigned short* __restrict__ xb) {
    long long gid = (long long)blockIdx.x * 256 + threadIdx.x;
    long long i8 = gid * 8;
    if (i8 >= (long long)MPAD * DD) return;
    int row = (int)(i8 >> 9);
    int col = (int)(i8 & 511);
    u16x8 ov;
    if (row < 2 * NN) {
        const float* src = (row < NN) ? (x1 + (size_t)row * DD + col)
                                      : (x2 + (size_t)(row - NN) * DD + col);
        float4 f0 = ((const float4*)src)[0];
        float4 f1 = ((const float4*)src)[1];
        ov[0] = f2bf(f0.x); ov[1] = f2bf(f0.y); ov[2] = f2bf(f0.z); ov[3] = f2bf(f0.w);
        ov[4] = f2bf(f1.x); ov[5] = f2bf(f1.y); ov[6] = f2bf(f1.z); ov[7] = f2bf(f1.w);
    } else {
        #pragma unroll
        for (int j = 0; j < 8; ++j) ov[j] = 0;
    }
    *(u16x8*)(xb + i8) = ov;
}

// W[k][n] fp32 -> Wt[n][k] bf16 (transpose so B-fragments load like A-fragments)
__global__ void k_cvt_w(const float* __restrict__ W1, const float* __restrict__ W2,
                        const float* __restrict__ W3, unsigned short* __restrict__ Wt) {
    __shared__ float t[32][33];
    const float* W = (blockIdx.z == 0) ? W1 : (blockIdx.z == 1) ? W2 : W3;
    unsigned short* o = Wt + (size_t)blockIdx.z * DD * DD;
    int n0 = blockIdx.x * 32, k0 = blockIdx.y * 32;
    int tx = threadIdx.x, ty = threadIdx.y;
    t[ty][tx] = W[(size_t)(k0 + ty) * DD + n0 + tx];
    __syncthreads();
    o[(size_t)(n0 + ty) * DD + k0 + tx] = f2bf(t[tx][ty]);
}

// ---------------------------------------------------------------------------
// bf16 MFMA GEMM: C[M x 512] = A[M x 512] * W[512 x 512], W given transposed.
// 128x128 tile, 4 waves (2x2), BK=32, 16x16x32 MFMA, global_load_lds width-16.
// LDS layout: 16B chunks at (kb*128 + row)*16 -> conflict-free ds_read_b128
// and linear lane->LDS mapping for global_load_lds (G21).
__global__ __launch_bounds__(256) void k_gemm(const unsigned short* __restrict__ A,
                                              const unsigned short* __restrict__ Bt,
                                              unsigned short* __restrict__ C, int M) {
    __shared__ bf16x8 As[512];   // 8 KB
    __shared__ bf16x8 Bs[512];   // 8 KB
    int tid = threadIdx.x;
    int lane = tid & 63;
    int wid = tid >> 6;
    int wr = wid >> 1, wc = wid & 1;
    int row0 = blockIdx.x * 128;
    int col0 = blockIdx.y * 128;

    // staging chunks: instr s in {0,1}: chunk = (s*4 + wid)*64 + lane
    int ch0 = wid * 64 + lane;
    int ch1 = 256 + wid * 64 + lane;
    const unsigned short* gA0 = A + (size_t)(row0 + (ch0 & 127)) * DD + (ch0 >> 7) * 8;
    const unsigned short* gA1 = A + (size_t)(row0 + (ch1 & 127)) * DD + (ch1 >> 7) * 8;
    const unsigned short* gB0 = Bt + (size_t)(col0 + (ch0 & 127)) * DD + (ch0 >> 7) * 8;
    const unsigned short* gB1 = Bt + (size_t)(col0 + (ch1 & 127)) * DD + (ch1 >> 7) * 8;

    // fragment LDS indices (fixed across K-loop)
    int iA[4], iB[4];
    #pragma unroll
    for (int m = 0; m < 4; ++m) {
        iA[m] = (lane >> 4) * 128 + wr * 64 + m * 16 + (lane & 15);
        iB[m] = (lane >> 4) * 128 + wc * 64 + m * 16 + (lane & 15);
    }

    f32x4 acc[4][4];
    #pragma unroll
    for (int m = 0; m < 4; ++m)
        #pragma unroll
        for (int n = 0; n < 4; ++n)
            acc[m][n] = (f32x4){0.f, 0.f, 0.f, 0.f};

    for (int k0 = 0; k0 < DD; k0 += 32) {
        GLOAD16(gA0, &As[wid * 64]);
        GLOAD16(gA1, &As[256 + wid * 64]);
        GLOAD16(gB0, &Bs[wid * 64]);
        GLOAD16(gB1, &Bs[256 + wid * 64]);
        gA0 += 32; gA1 += 32; gB0 += 32; gB1 += 32;
        __syncthreads();                       // drain vmcnt + barrier
        bf16x8 af[4], bfr[4];
        #pragma unroll
        for (int m = 0; m < 4; ++m) { af[m] = As[iA[m]]; bfr[m] = Bs[iB[m]]; }
        #pragma unroll
        for (int m = 0; m < 4; ++m)
            #pragma unroll
            for (int n = 0; n < 4; ++n)
                acc[m][n] = __builtin_amdgcn_mfma_f32_16x16x32_bf16(af[m], bfr[n], acc[m][n], 0, 0, 0);
        __syncthreads();                       // protect LDS before next stage
    }

    // epilogue: C/D layout col = lane&15, row = (lane>>4)*4 + i  [m89]
    #pragma unroll
    for (int m = 0; m < 4; ++m) {
        int rbase = row0 + wr * 64 + m * 16 + (lane >> 4) * 4;
        #pragma unroll
        for (int n = 0; n < 4; ++n) {
            int col = col0 + wc * 64 + n * 16 + (lane & 15);
            f32x4 v = acc[m][n];
            #pragma unroll
            for (int i = 0; i < 4; ++i) {
                int r = rbase + i;
                if (r < M) C[(size_t)r * DD + col] = f2bf(v[i]);
            }
        }
    }
}

// ---------------------------------------------------------------------------
// aggregation: out[v] = maybe_relu( dv*(sum_{s->v} h[s]*ds + h[v]*dv) + b )
// one wave per node, lane owns 8 cols (16B ushort8 loads), fp32 accumulate.
// Edge loop unrolled x4 for memory-level parallelism on the gather.
template <bool RELU>
__global__ __launch_bounds__(256) void k_agg(const unsigned short* __restrict__ h,
                                             const int* __restrict__ adj,
                                             const int* __restrict__ offs,
                                             const float* __restrict__ dinv,
                                             const float* __restrict__ bias,
                                             unsigned short* __restrict__ out) {
    int wid = threadIdx.x >> 6;
    int lane = threadIdx.x & 63;
    int v = blockIdx.x * 4 + wid;       // 0 .. 2*NN-1 (grid exact)
    int g = (v < NN) ? 0 : 1;
    int vl = v - g * NN;
    const int* o = offs + g * (NN + 1);
    int beg = o[vl], end = o[vl + 1];
    const int* a = adj + g * NE;
    float dv = dinv[v];
    int c = lane * 8;
    const unsigned short* hb = h + c;
    int gbase = g * NN;

    u16x8 hv = *(const u16x8*)(hb + (size_t)v * DD);
    float acc[8];
    #pragma unroll
    for (int j = 0; j < 8; ++j) acc[j] = bf2f(hv[j]) * dv;   // self-loop term

    int e = beg;
    for (; e + 4 <= end; e += 4) {
        int s0 = a[e] + gbase, s1 = a[e + 1] + gbase;
        int s2 = a[e + 2] + gbase, s3 = a[e + 3] + gbase;
        u16x8 r0 = *(const u16x8*)(hb + (size_t)s0 * DD);
        u16x8 r1 = *(const u16x8*)(hb + (size_t)s1 * DD);
        u16x8 r2 = *(const u16x8*)(hb + (size_t)s2 * DD);
        u16x8 r3 = *(const u16x8*)(hb + (size_t)s3 * DD);
        float d0 = dinv[s0], d1 = dinv[s1], d2 = dinv[s2], d3 = dinv[s3];
        #pragma unroll
        for (int j = 0; j < 8; ++j) {
            acc[j] = fmaf(bf2f(r0[j]), d0, acc[j]);
            acc[j] = fmaf(bf2f(r1[j]), d1, acc[j]);
            acc[j] = fmaf(bf2f(r2[j]), d2, acc[j]);
            acc[j] = fmaf(bf2f(r3[j]), d3, acc[j]);
        }
    }
    for (; e < end; ++e) {
        int s = a[e] + gbase;
        float ds = dinv[s];
        u16x8 hs = *(const u16x8*)(hb + (size_t)s * DD);
        #pragma unroll
        for (int j = 0; j < 8; ++j) acc[j] = fmaf(bf2f(hs[j]), ds, acc[j]);
    }

    float4 b0 = ((const float4*)(bias + c))[0];
    float4 b1 = ((const float4*)(bias + c))[1];
    float bb[8] = {b0.x, b0.y, b0.z, b0.w, b1.x, b1.y, b1.z, b1.w};
    u16x8 ov;
    #pragma unroll
    for (int j = 0; j < 8; ++j) {
        float x = fmaf(acc[j], dv, bb[j]);
        if (RELU) x = fmaxf(x, 0.f);
        ov[j] = f2bf(x);
    }
    *(u16x8*)(out + (size_t)v * DD + c) = ov;
}

// ---------------------------------------------------------------------------
// column sums for the per-graph mean: 2 x 128 blocks, 4 waves row-interleaved,
// ushort8 loads (full row per wave-load), LDS cross-wave reduce, 1 atomic/col.
__global__ __launch_bounds__(256) void k_meanpart(const unsigned short* __restrict__ h,
                                                  float* __restrict__ u) {
    __shared__ float sm[4][DD];
    int g = blockIdx.y;
    int chunk = blockIdx.x;              // 0..127
    int wid = threadIdx.x >> 6;
    int lane = threadIdx.x & 63;
    int c = lane * 8;
    const int rows_per = (NN + 127) / 128;   // 79
    int r0 = chunk * rows_per;
    int r1 = min(r0 + rows_per, NN);
    float acc[8] = {0.f, 0.f, 0.f, 0.f, 0.f, 0.f, 0.f, 0.f};
    for (int r = r0 + wid; r < r1; r += 4) {
        u16x8 hv = *(const u16x8*)(h + (size_t)(g * NN + r) * DD + c);
        #pragma unroll
        for (int j = 0; j < 8; ++j) acc[j] += bf2f(hv[j]);
    }
    #pragma unroll
    for (int j = 0; j < 8; ++j) sm[wid][c + j] = acc[j];
    __syncthreads();
    if (wid == 0) {
        #pragma unroll
        for (int j = 0; j < 8; ++j) {
            float s = sm[0][c + j] + sm[1][c + j] + sm[2][c + j] + sm[3][c + j];
            atomicAdd(&u[g * DD + c + j], s);
        }
    }
}

// head part 1: hacc[t] += sum_k z[k] * Wf1[k][t], k split over 8 blocks
__global__ void k_head1(const float* __restrict__ u, const float* __restrict__ Wf1,
                        float* __restrict__ hacc) {
    int t = threadIdx.x;                 // 512
    int kb = blockIdx.x;                 // 8 blocks x 128 k
    const float inv = 1.0f / (float)NN;
    float acc = 0.f;
    for (int k = kb * 128; k < kb * 128 + 128; ++k) {
        float z = u[k] * inv;
        acc = fmaf(z, Wf1[(size_t)k * DD + t], acc);
    }
    atomicAdd(&hacc[t], acc);
}

// head part 2: relu + dot + sigmoid
__global__ void k_head2(const float* __restrict__ hacc, const float* __restrict__ bf1,
                        const float* __restrict__ Wf2, const float* __restrict__ bf2,
                        float* __restrict__ outp) {
    __shared__ float red[DD];
    int t = threadIdx.x;                 // 512
    float hv = fmaxf(hacc[t] + bf1[t], 0.f);
    red[t] = hv * Wf2[t];
    __syncthreads();
    for (int s = DD / 2; s > 0; s >>= 1) {
        if (t < s) red[t] += red[t + s];
        __syncthreads();
    }
    if (t == 0) outp[0] = 1.f / (1.f + expf(-(red[0] + bf2[0])));
}

// ---------------------------------------------------------------------------
extern "C" void kernel_launch(void* const* d_in, const int* in_sizes, int n_in,
                              void* d_out, int out_size, void* d_ws, size_t ws_size,
                              hipStream_t stream) {
    const float* x1  = (const float*)d_in[0];
    const float* x2  = (const float*)d_in[1];
    const int*   e1  = (const int*)d_in[2];
    const int*   e2  = (const int*)d_in[3];
    const float* W1  = (const float*)d_in[4];
    const float* W2  = (const float*)d_in[5];
    const float* W3  = (const float*)d_in[6];
    const float* b1  = (const float*)d_in[7];
    const float* b2  = (const float*)d_in[8];
    const float* b3  = (const float*)d_in[9];
    const float* Wf1 = (const float*)d_in[10];
    const float* bf1 = (const float*)d_in[11];
    const float* Wf2 = (const float*)d_in[12];
    const float* bf2 = (const float*)d_in[13];
    float* outp = (float*)d_out;

    // workspace carve-up (16B-aligned chunks)
    char* w = (char*)d_ws;
    unsigned short* xb = (unsigned short*)w; w += (size_t)MPAD * DD * 2;   // 20.6 MB
    unsigned short* hG = (unsigned short*)w; w += (size_t)MPAD * DD * 2;   // 20.6 MB
    unsigned short* hA = (unsigned short*)w; w += (size_t)MPAD * DD * 2;   // 20.6 MB
    unsigned short* Wt = (unsigned short*)w; w += (size_t)3 * DD * DD * 2; // 1.5 MB
    int*   cnt    = (int*)w;   w += 2 * NN * 4;
    int*   cursor = (int*)w;   w += 2 * NN * 4;
    int*   offs   = (int*)w;   w += 2 * (NN + 1) * 4 + 8;
    int*   adj    = (int*)w;   w += 2 * NE * 4;
    float* dinv   = (float*)w; w += 2 * NN * 4;
    float* u      = (float*)w; w += 2 * DD * 4;
    float* hacc   = (float*)w; w += DD * 4;

    const int M = 2 * NN;

    // graph preprocessing + conversions
    k_init<<<(2 * NN + 255) / 256, 256, 0, stream>>>(cnt, cursor, u, hacc);
    k_count<<<(2 * NE + 255) / 256, 256, 0, stream>>>(e1, e2, cnt);
    k_dinv<<<(2 * NN + 255) / 256, 256, 0, stream>>>(cnt, dinv);
    k_scan<<<2, 1024, 0, stream>>>(cnt, offs);
    k_fill<<<(2 * NE + 255) / 256, 256, 0, stream>>>(e1, e2, offs, cursor, adj);
    k_cvt_x<<<(MPAD * DD / 8 + 255) / 256, 256, 0, stream>>>(x1, x2, xb);
    k_cvt_w<<<dim3(16, 16, 3), dim3(32, 32), 0, stream>>>(W1, W2, W3, Wt);

    dim3 ggrid(MPAD / 128, DD / 128);   // 157 x 4

    // layer 1
    k_gemm<<<ggrid, 256, 0, stream>>>(xb, Wt, hG, M);
    k_agg<true><<<M / 4, 256, 0, stream>>>(hG, adj, offs, dinv, b1, hA);
    // layer 2
    k_gemm<<<ggrid, 256, 0, stream>>>(hA, Wt + (size_t)DD * DD, hG, M);
    k_agg<true><<<M / 4, 256, 0, stream>>>(hG, adj, offs, dinv, b2, hA);
    // layer 3
    k_gemm<<<ggrid, 256, 0, stream>>>(hA, Wt + (size_t)2 * DD * DD, hG, M);
    k_agg<false><<<M / 4, 256, 0, stream>>>(hG, adj, offs, dinv, b3, hA);

    // mean + head
    k_meanpart<<<dim3(128, 2), 256, 0, stream>>>(hA, u);
    k_head1<<<8, DD, 0, stream>>>(u, Wf1, hacc);
    k_head2<<<1, DD, 0, stream>>>(hacc, bf1, Wf2, bf2, outp);
}

// Round 4
// 296.693 us; speedup vs baseline: 2.8263x; 1.1125x over previous
//
#include <hip/hip_runtime.h>
#include <math.h>

#define NN 10000       // nodes per graph
#define NE 160000      // edges per graph
#define DD 512         // feature dim
#define MPAD 20096     // 157 * 128 rows (padded batched M)

typedef __attribute__((ext_vector_type(8))) short bf16x8;
typedef __attribute__((ext_vector_type(4))) float f32x4;
typedef __attribute__((ext_vector_type(8))) unsigned short u16x8;

__device__ __forceinline__ unsigned short f2bf(float f) {
    unsigned u = __float_as_uint(f);
    u += 0x7FFFu + ((u >> 16) & 1u);          // round-to-nearest-even
    return (unsigned short)(u >> 16);
}
__device__ __forceinline__ float bf2f(unsigned short h) {
    return __uint_as_float(((unsigned)h) << 16);
}

// async global->LDS, 16B per lane; LDS dest is wave-uniform base + lane*16
#define GLOAD16(g, l) __builtin_amdgcn_global_load_lds( \
    (const __attribute__((address_space(1))) void*)(unsigned long long)(const void*)(g), \
    (__attribute__((address_space(3))) void*)(unsigned)(unsigned long long)(void*)(l), \
    16, 0, 0)

// ---------------------------------------------------------------------------
// init: zero edge counts, cursors, mean accumulators, head accumulator
__global__ void k_init(int* cnt, int* cursor, float* u, float* hacc) {
    int i = blockIdx.x * blockDim.x + threadIdx.x;
    if (i < 2 * NN) { cnt[i] = 0; cursor[i] = 0; }
    if (i < 2 * DD) u[i] = 0.f;
    if (i < DD) hacc[i] = 0.f;
}

// count in-degree (real edges only; self-loop handled as +1 later)
__global__ void k_count(const int* e1, const int* e2, int* cnt) {
    int i = blockIdx.x * blockDim.x + threadIdx.x;
    if (i < NE) {
        atomicAdd(&cnt[e1[NE + i]], 1);
    } else if (i < 2 * NE) {
        int e = i - NE;
        atomicAdd(&cnt[NN + e2[NE + e]], 1);
    }
}

__global__ void k_dinv(const int* cnt, float* dinv) {
    int i = blockIdx.x * blockDim.x + threadIdx.x;
    if (i < 2 * NN) dinv[i] = rsqrtf((float)(cnt[i] + 1));
}

// exclusive scan of per-node edge counts -> CSR offsets. One block per graph.
__global__ void k_scan(const int* cnt, int* offs) {
    int g = blockIdx.x;
    const int* c = cnt + g * NN;
    int* o = offs + g * (NN + 1);
    __shared__ int sums[1024];
    int t = threadIdx.x;                  // 1024 threads
    const int PER = 10;                   // 1024*10 >= NN
    int base = t * PER;
    int vals[PER];
    int local = 0;
    #pragma unroll
    for (int j = 0; j < PER; ++j) {
        int idx = base + j;
        int v = (idx < NN) ? c[idx] : 0;
        vals[j] = v; local += v;
    }
    sums[t] = local;
    __syncthreads();
    for (int off = 1; off < 1024; off <<= 1) {
        int v = (t >= off) ? sums[t - off] : 0;
        __syncthreads();
        sums[t] += v;
        __syncthreads();
    }
    int prefix = (t > 0) ? sums[t - 1] : 0;   // exclusive
    #pragma unroll
    for (int j = 0; j < PER; ++j) {
        int idx = base + j;
        if (idx < NN) { o[idx] = prefix; prefix += vals[j]; }
    }
    if (t == 1023) o[NN] = sums[1023];
}

// scatter edges into CSR buckets (adj holds SRC node per incoming edge of dst)
__global__ void k_fill(const int* e1, const int* e2, const int* offs,
                       int* cursor, int* adj) {
    int i = blockIdx.x * blockDim.x + threadIdx.x;
    if (i >= 2 * NE) return;
    int g = (i < NE) ? 0 : 1;
    int e = i - g * NE;
    const int* ei = g ? e2 : e1;
    int s = ei[e];
    int d = ei[NE + e];
    int pos = atomicAdd(&cursor[g * NN + d], 1);
    adj[g * NE + offs[g * (NN + 1) + d] + pos] = s;
}

// ---------------------------------------------------------------------------
// fp32 -> bf16 convert of node features, both graphs batched, tail rows zeroed
__global__ void k_cvt_x(const float* __restrict__ x1, const float* __restrict__ x2,
                        unsigned short* __restrict__ xb) {
    long long gid = (long long)blockIdx.x * 256 + threadIdx.x;
    long long i8 = gid * 8;
    if (i8 >= (long long)MPAD * DD) return;
    int row = (int)(i8 >> 9);
    int col = (int)(i8 & 511);
    u16x8 ov;
    if (row < 2 * NN) {
        const float* src = (row < NN) ? (x1 + (size_t)row * DD + col)
                                      : (x2 + (size_t)(row - NN) * DD + col);
        float4 f0 = ((const float4*)src)[0];
        float4 f1 = ((const float4*)src)[1];
        ov[0] = f2bf(f0.x); ov[1] = f2bf(f0.y); ov[2] = f2bf(f0.z); ov[3] = f2bf(f0.w);
        ov[4] = f2bf(f1.x); ov[5] = f2bf(f1.y); ov[6] = f2bf(f1.z); ov[7] = f2bf(f1.w);
    } else {
        #pragma unroll
        for (int j = 0; j < 8; ++j) ov[j] = 0;
    }
    *(u16x8*)(xb + i8) = ov;
}

// W[k][n] fp32 -> Wt[n][k] bf16 (transpose so B-fragments load like A-fragments)
__global__ void k_cvt_w(const float* __restrict__ W1, const float* __restrict__ W2,
                        const float* __restrict__ W3, unsigned short* __restrict__ Wt) {
    __shared__ float t[32][33];
    const float* W = (blockIdx.z == 0) ? W1 : (blockIdx.z == 1) ? W2 : W3;
    unsigned short* o = Wt + (size_t)blockIdx.z * DD * DD;
    int n0 = blockIdx.x * 32, k0 = blockIdx.y * 32;
    int tx = threadIdx.x, ty = threadIdx.y;
    t[ty][tx] = W[(size_t)(k0 + ty) * DD + n0 + tx];
    __syncthreads();
    o[(size_t)(n0 + ty) * DD + k0 + tx] = f2bf(t[tx][ty]);
}

// ---------------------------------------------------------------------------
// bf16 MFMA GEMM: C[M x 512] = A[M x 512] * W[512 x 512], W given transposed.
// 128x128 tile, 4 waves (2x2), BK=32, 16x16x32 MFMA, global_load_lds width-16.
// LDS layout: 16B chunks at (kb*128 + row)*16 -> conflict-free ds_read_b128
// and linear lane->LDS mapping for global_load_lds (G21).
__global__ __launch_bounds__(256) void k_gemm(const unsigned short* __restrict__ A,
                                              const unsigned short* __restrict__ Bt,
                                              unsigned short* __restrict__ C, int M) {
    __shared__ bf16x8 As[512];   // 8 KB
    __shared__ bf16x8 Bs[512];   // 8 KB
    int tid = threadIdx.x;
    int lane = tid & 63;
    int wid = tid >> 6;
    int wr = wid >> 1, wc = wid & 1;
    int row0 = blockIdx.x * 128;
    int col0 = blockIdx.y * 128;

    // staging chunks: instr s in {0,1}: chunk = (s*4 + wid)*64 + lane
    int ch0 = wid * 64 + lane;
    int ch1 = 256 + wid * 64 + lane;
    const unsigned short* gA0 = A + (size_t)(row0 + (ch0 & 127)) * DD + (ch0 >> 7) * 8;
    const unsigned short* gA1 = A + (size_t)(row0 + (ch1 & 127)) * DD + (ch1 >> 7) * 8;
    const unsigned short* gB0 = Bt + (size_t)(col0 + (ch0 & 127)) * DD + (ch0 >> 7) * 8;
    const unsigned short* gB1 = Bt + (size_t)(col0 + (ch1 & 127)) * DD + (ch1 >> 7) * 8;

    // fragment LDS indices (fixed across K-loop)
    int iA[4], iB[4];
    #pragma unroll
    for (int m = 0; m < 4; ++m) {
        iA[m] = (lane >> 4) * 128 + wr * 64 + m * 16 + (lane & 15);
        iB[m] = (lane >> 4) * 128 + wc * 64 + m * 16 + (lane & 15);
    }

    f32x4 acc[4][4];
    #pragma unroll
    for (int m = 0; m < 4; ++m)
        #pragma unroll
        for (int n = 0; n < 4; ++n)
            acc[m][n] = (f32x4){0.f, 0.f, 0.f, 0.f};

    for (int k0 = 0; k0 < DD; k0 += 32) {
        GLOAD16(gA0, &As[wid * 64]);
        GLOAD16(gA1, &As[256 + wid * 64]);
        GLOAD16(gB0, &Bs[wid * 64]);
        GLOAD16(gB1, &Bs[256 + wid * 64]);
        gA0 += 32; gA1 += 32; gB0 += 32; gB1 += 32;
        __syncthreads();                       // drain vmcnt + barrier
        bf16x8 af[4], bfr[4];
        #pragma unroll
        for (int m = 0; m < 4; ++m) { af[m] = As[iA[m]]; bfr[m] = Bs[iB[m]]; }
        #pragma unroll
        for (int m = 0; m < 4; ++m)
            #pragma unroll
            for (int n = 0; n < 4; ++n)
                acc[m][n] = __builtin_amdgcn_mfma_f32_16x16x32_bf16(af[m], bfr[n], acc[m][n], 0, 0, 0);
        __syncthreads();                       // protect LDS before next stage
    }

    // epilogue: C/D layout col = lane&15, row = (lane>>4)*4 + i  [m89]
    #pragma unroll
    for (int m = 0; m < 4; ++m) {
        int rbase = row0 + wr * 64 + m * 16 + (lane >> 4) * 4;
        #pragma unroll
        for (int n = 0; n < 4; ++n) {
            int col = col0 + wc * 64 + n * 16 + (lane & 15);
            f32x4 v = acc[m][n];
            #pragma unroll
            for (int i = 0; i < 4; ++i) {
                int r = rbase + i;
                if (r < M) C[(size_t)r * DD + col] = f2bf(v[i]);
            }
        }
    }
}

// ---------------------------------------------------------------------------
// column-split aggregation: out[v, cc] = maybe_relu(dv*(sum h[s,cc]*ds + h[v,cc]*dv) + b)
// Grid = 625*8 blocks; combo = bid&7 = (graph<<2)|colchunk pins each
// (graph, 128-col slice) to one XCD (round-robin dispatch) -> gather working
// set 10000x128x2B = 2.56 MB fits the 4 MB per-XCD L2.
// Wave = 4 nodes x 16 lanes (ushort8 = 128 cols); edge loop unrolled x4.
template <bool RELU>
__global__ __launch_bounds__(256) void k_aggc(const unsigned short* __restrict__ h,
                                              const int* __restrict__ adj,
                                              const int* __restrict__ offs,
                                              const float* __restrict__ dinv,
                                              const float* __restrict__ bias,
                                              unsigned short* __restrict__ out) {
    int bid = blockIdx.x;
    int combo = bid & 7;                 // -> XCD (perf heuristic only)
    int nb = bid >> 3;                   // 0..624
    int g = combo >> 2;
    int yc = combo & 3;
    int wid = threadIdx.x >> 6;
    int lane = threadIdx.x & 63;
    int sub = lane >> 4;                 // node within wave
    int li = lane & 15;                  // col lane
    int v = nb * 16 + wid * 4 + sub;     // 0..9999 (exact: 625*16 = 10000)
    int c = yc * 128 + li * 8;
    int gbase = g * NN;
    const int* o = offs + g * (NN + 1);
    int beg = o[v], end = o[v + 1];
    const int* a = adj + g * NE;
    float dv = dinv[gbase + v];
    const unsigned short* hb = h + c;

    u16x8 hv = *(const u16x8*)(hb + (size_t)(gbase + v) * DD);
    float acc[8];
    #pragma unroll
    for (int j = 0; j < 8; ++j) acc[j] = bf2f(hv[j]) * dv;   // self-loop term

    int e = beg;
    for (; e + 4 <= end; e += 4) {
        int s0 = a[e] + gbase, s1 = a[e + 1] + gbase;
        int s2 = a[e + 2] + gbase, s3 = a[e + 3] + gbase;
        u16x8 r0 = *(const u16x8*)(hb + (size_t)s0 * DD);
        u16x8 r1 = *(const u16x8*)(hb + (size_t)s1 * DD);
        u16x8 r2 = *(const u16x8*)(hb + (size_t)s2 * DD);
        u16x8 r3 = *(const u16x8*)(hb + (size_t)s3 * DD);
        float d0 = dinv[s0], d1 = dinv[s1], d2 = dinv[s2], d3 = dinv[s3];
        #pragma unroll
        for (int j = 0; j < 8; ++j) {
            acc[j] = fmaf(bf2f(r0[j]), d0, acc[j]);
            acc[j] = fmaf(bf2f(r1[j]), d1, acc[j]);
            acc[j] = fmaf(bf2f(r2[j]), d2, acc[j]);
            acc[j] = fmaf(bf2f(r3[j]), d3, acc[j]);
        }
    }
    for (; e < end; ++e) {
        int s = a[e] + gbase;
        float ds = dinv[s];
        u16x8 hs = *(const u16x8*)(hb + (size_t)s * DD);
        #pragma unroll
        for (int j = 0; j < 8; ++j) acc[j] = fmaf(bf2f(hs[j]), ds, acc[j]);
    }

    float4 b0 = ((const float4*)(bias + c))[0];
    float4 b1 = ((const float4*)(bias + c))[1];
    float bb[8] = {b0.x, b0.y, b0.z, b0.w, b1.x, b1.y, b1.z, b1.w};
    u16x8 ov;
    #pragma unroll
    for (int j = 0; j < 8; ++j) {
        float x = fmaf(acc[j], dv, bb[j]);
        if (RELU) x = fmaxf(x, 0.f);
        ov[j] = f2bf(x);
    }
    *(u16x8*)(out + (size_t)(gbase + v) * DD + c) = ov;
}

// ---------------------------------------------------------------------------
// column sums for the per-graph mean: 2 x 128 blocks, 4 waves row-interleaved,
// ushort8 loads (full row per wave-load), LDS cross-wave reduce, 1 atomic/col.
__global__ __launch_bounds__(256) void k_meanpart(const unsigned short* __restrict__ h,
                                                  float* __restrict__ u) {
    __shared__ float sm[4][DD];
    int g = blockIdx.y;
    int chunk = blockIdx.x;              // 0..127
    int wid = threadIdx.x >> 6;
    int lane = threadIdx.x & 63;
    int c = lane * 8;
    const int rows_per = (NN + 127) / 128;   // 79
    int r0 = chunk * rows_per;
    int r1 = min(r0 + rows_per, NN);
    float acc[8] = {0.f, 0.f, 0.f, 0.f, 0.f, 0.f, 0.f, 0.f};
    for (int r = r0 + wid; r < r1; r += 4) {
        u16x8 hv = *(const u16x8*)(h + (size_t)(g * NN + r) * DD + c);
        #pragma unroll
        for (int j = 0; j < 8; ++j) acc[j] += bf2f(hv[j]);
    }
    #pragma unroll
    for (int j = 0; j < 8; ++j) sm[wid][c + j] = acc[j];
    __syncthreads();
    if (wid == 0) {
        #pragma unroll
        for (int j = 0; j < 8; ++j) {
            float s = sm[0][c + j] + sm[1][c + j] + sm[2][c + j] + sm[3][c + j];
            atomicAdd(&u[g * DD + c + j], s);
        }
    }
}

// head part 1: hacc[t] += sum_k z[k] * Wf1[k][t], k split over 8 blocks
__global__ void k_head1(const float* __restrict__ u, const float* __restrict__ Wf1,
                        float* __restrict__ hacc) {
    int t = threadIdx.x;                 // 512
    int kb = blockIdx.x;                 // 8 blocks x 128 k
    const float inv = 1.0f / (float)NN;
    float acc = 0.f;
    for (int k = kb * 128; k < kb * 128 + 128; ++k) {
        float z = u[k] * inv;
        acc = fmaf(z, Wf1[(size_t)k * DD + t], acc);
    }
    atomicAdd(&hacc[t], acc);
}

// head part 2: relu + dot + sigmoid
__global__ void k_head2(const float* __restrict__ hacc, const float* __restrict__ bf1,
                        const float* __restrict__ Wf2, const float* __restrict__ bf2,
                        float* __restrict__ outp) {
    __shared__ float red[DD];
    int t = threadIdx.x;                 // 512
    float hv = fmaxf(hacc[t] + bf1[t], 0.f);
    red[t] = hv * Wf2[t];
    __syncthreads();
    for (int s = DD / 2; s > 0; s >>= 1) {
        if (t < s) red[t] += red[t + s];
        __syncthreads();
    }
    if (t == 0) outp[0] = 1.f / (1.f + expf(-(red[0] + bf2[0])));
}

// ---------------------------------------------------------------------------
extern "C" void kernel_launch(void* const* d_in, const int* in_sizes, int n_in,
                              void* d_out, int out_size, void* d_ws, size_t ws_size,
                              hipStream_t stream) {
    const float* x1  = (const float*)d_in[0];
    const float* x2  = (const float*)d_in[1];
    const int*   e1  = (const int*)d_in[2];
    const int*   e2  = (const int*)d_in[3];
    const float* W1  = (const float*)d_in[4];
    const float* W2  = (const float*)d_in[5];
    const float* W3  = (const float*)d_in[6];
    const float* b1  = (const float*)d_in[7];
    const float* b2  = (const float*)d_in[8];
    const float* b3  = (const float*)d_in[9];
    const float* Wf1 = (const float*)d_in[10];
    const float* bf1 = (const float*)d_in[11];
    const float* Wf2 = (const float*)d_in[12];
    const float* bf2 = (const float*)d_in[13];
    float* outp = (float*)d_out;

    // workspace carve-up (16B-aligned chunks)
    char* w = (char*)d_ws;
    unsigned short* xb = (unsigned short*)w; w += (size_t)MPAD * DD * 2;   // 20.6 MB
    unsigned short* hG = (unsigned short*)w; w += (size_t)MPAD * DD * 2;   // 20.6 MB
    unsigned short* hA = (unsigned short*)w; w += (size_t)MPAD * DD * 2;   // 20.6 MB
    unsigned short* Wt = (unsigned short*)w; w += (size_t)3 * DD * DD * 2; // 1.5 MB
    int*   cnt    = (int*)w;   w += 2 * NN * 4;
    int*   cursor = (int*)w;   w += 2 * NN * 4;
    int*   offs   = (int*)w;   w += 2 * (NN + 1) * 4 + 8;
    int*   adj    = (int*)w;   w += 2 * NE * 4;
    float* dinv   = (float*)w; w += 2 * NN * 4;
    float* u      = (float*)w; w += 2 * DD * 4;
    float* hacc   = (float*)w; w += DD * 4;

    const int M = 2 * NN;

    // graph preprocessing + conversions
    k_init<<<(2 * NN + 255) / 256, 256, 0, stream>>>(cnt, cursor, u, hacc);
    k_count<<<(2 * NE + 255) / 256, 256, 0, stream>>>(e1, e2, cnt);
    k_dinv<<<(2 * NN + 255) / 256, 256, 0, stream>>>(cnt, dinv);
    k_scan<<<2, 1024, 0, stream>>>(cnt, offs);
    k_fill<<<(2 * NE + 255) / 256, 256, 0, stream>>>(e1, e2, offs, cursor, adj);
    k_cvt_x<<<(MPAD * DD / 8 + 255) / 256, 256, 0, stream>>>(x1, x2, xb);
    k_cvt_w<<<dim3(16, 16, 3), dim3(32, 32), 0, stream>>>(W1, W2, W3, Wt);

    dim3 ggrid(MPAD / 128, DD / 128);   // 157 x 4
    const int aggGrid = (NN / 16) * 8;  // 625 node-chunks x 8 (graph,colchunk) combos

    // layer 1
    k_gemm<<<ggrid, 256, 0, stream>>>(xb, Wt, hG, M);
    k_aggc<true><<<aggGrid, 256, 0, stream>>>(hG, adj, offs, dinv, b1, hA);
    // layer 2
    k_gemm<<<ggrid, 256, 0, stream>>>(hA, Wt + (size_t)DD * DD, hG, M);
    k_aggc<true><<<aggGrid, 256, 0, stream>>>(hG, adj, offs, dinv, b2, hA);
    // layer 3
    k_gemm<<<ggrid, 256, 0, stream>>>(hA, Wt + (size_t)2 * DD * DD, hG, M);
    k_aggc<false><<<aggGrid, 256, 0, stream>>>(hG, adj, offs, dinv, b3, hA);

    // mean + head
    k_meanpart<<<dim3(128, 2), 256, 0, stream>>>(hA, u);
    k_head1<<<8, DD, 0, stream>>>(u, Wf1, hacc);
    k_head2<<<1, DD, 0, stream>>>(hacc, bf1, Wf2, bf2, outp);
}